// Round 16
// baseline (1589.881 us; speedup 1.0000x reference)
//
#include <hip/hip_runtime.h>

#define KU 512
#define NB 32
#define NT 64
#define TIL 64
#define SLOTS 16
#define NBMAX 40

// ---- ws float offsets ----
#define N_PONG   (KU * NB * 90)
#define OFF_CEB  (N_PONG)                    // ce_sync+b_sync [512][90] f32
#define OFF_GI0  (OFF_CEB + KU * 90)         // gi0 [272] f32
#define OFF_WHTF (OFF_GI0 + 288)             // us[3][6][3][64][8] Wh       (27648 us)
#define OFF_SYF  (OFF_WHTF + 13824)          // us[6][3][64][8]    Wsync_lo (9216 us)
#define OFF_AGF  (OFF_SYF + 4608)            // us[6][3][64][8]    W_agg    (9216 us)
#define OFF_WIF  (OFF_AGF + 4608)            // us[17][3][64][8]   Wi_rnn   (26112 us)
#define OFF_WISF (OFF_WIF + 13056)           // us[17][3][64][8]   Wi_self  (26112 us)
#define OFF_WHSF (OFF_WISF + 13056)          // us[17][3][64][8]   Wh_self  (26112 us)
#define OFF_SYMF (OFF_WHSF + 13056)          // us[6][3][64][8]    Wsync_mid(9216 us)
#define OFF_WPRF (OFF_SYMF + 4608)           // us[6][6][64][8]    W_prop   (18432 us)

typedef short bf16x8 __attribute__((ext_vector_type(8)));
typedef float f32x4 __attribute__((ext_vector_type(4)));

__device__ __forceinline__ float sigf(float x) { return 1.0f / (1.0f + __expf(-x)); }
__device__ __forceinline__ float tanhf_(float x) {
    float e = __expf(2.0f * x);
    return 1.0f - 2.0f / (e + 1.0f);
}
__device__ __forceinline__ unsigned short f2bf(float f) {
    union { float f; unsigned u; } v; v.f = f;
    unsigned r = v.u + 0x7FFFu + ((v.u >> 16) & 1u);
    return (unsigned short)(r >> 16);
}
__device__ __forceinline__ bf16x8 cvt8(const float* p) {
    const float4 a0 = *(const float4*)p;
    const float4 a1 = *(const float4*)(p + 4);
    union { bf16x8 v; unsigned short u[8]; } fr;
    fr.u[0] = f2bf(a0.x); fr.u[1] = f2bf(a0.y); fr.u[2] = f2bf(a0.z); fr.u[3] = f2bf(a0.w);
    fr.u[4] = f2bf(a1.x); fr.u[5] = f2bf(a1.y); fr.u[6] = f2bf(a1.z); fr.u[7] = f2bf(a1.w);
    return fr.v;
}
__device__ __forceinline__ f32x4 mm3(const bf16x8* af, const unsigned short* bp) {
    f32x4 d = f32x4{0.f, 0.f, 0.f, 0.f};
    d = __builtin_amdgcn_mfma_f32_16x16x32_bf16(af[0], *(const bf16x8*)(bp), d, 0, 0, 0);
    d = __builtin_amdgcn_mfma_f32_16x16x32_bf16(af[1], *(const bf16x8*)(bp + 512), d, 0, 0, 0);
    d = __builtin_amdgcn_mfma_f32_16x16x32_bf16(af[2], *(const bf16x8*)(bp + 1024), d, 0, 0, 0);
    return d;
}

// ============ prep: ce_sync + gi0 + all bf16 weight fragments (once) ============
__global__ void skt_prep(const float* __restrict__ concept_emb, const float* __restrict__ W_sync,
                         const float* __restrict__ b_sync, const float* __restrict__ Wi_rnn,
                         const float* __restrict__ Wh_rnn, const float* __restrict__ Wi_self,
                         const float* __restrict__ Wh_self, const float* __restrict__ W_prop,
                         const float* __restrict__ bi_rnn, const float* __restrict__ b_agg,
                         const float* __restrict__ W_agg, float* __restrict__ ws) {
    const int blk = blockIdx.x, tid = threadIdx.x;
    if (blk < 128) {                       // ceb[512][90]
        for (int rr = 0; rr < 4; ++rr) {
            const int k = blk * 4 + rr;
            if (tid < 90) {
                float acc = b_sync[tid];
                for (int kk = 0; kk < 90; ++kk)
                    acc += concept_emb[k * 90 + kk] * W_sync[(180 + kk) * 90 + tid];
                ws[OFF_CEB + k * 90 + tid] = acc;
            }
        }
    } else if (blk < 131) {                // whtF
        const int g = blk - 128;
        unsigned short* p = (unsigned short*)(ws + OFF_WHTF);
        for (int idx = tid; idx < 9216; idx += 256) {
            const int i = idx & 7, lane = (idx >> 3) & 63;
            const int rest = idx >> 9, kk = rest % 3, nb = rest / 3;
            const int n = nb * 16 + (lane & 15);
            const int k = kk * 32 + ((lane >> 4) << 3) + i;
            p[(size_t)g * 9216 + idx] = f2bf((n < 90 && k < 90) ? Wh_rnn[k * 270 + g * 90 + n] : 0.f);
        }
    } else if (blk == 131) {               // gi0
        for (int c = tid; c < 272; c += 256) {
            float acc = 0.f;
            if (c < 270) {
                acc = bi_rnn[c];
                for (int kk = 0; kk < 90; ++kk)
                    acc += fmaxf(b_agg[kk], 0.f) * Wi_rnn[kk * 270 + c];
            }
            ws[OFF_GI0 + c] = acc;
        }
    } else if (blk == 132) {               // syF
        unsigned short* p = (unsigned short*)(ws + OFF_SYF);
        for (int idx = tid; idx < 9216; idx += 256) {
            const int i = idx & 7, lane = (idx >> 3) & 63;
            const int rest = idx >> 9, kk = rest % 3, nt = rest / 3;
            const int n = nt * 16 + (lane & 15);
            const int k = kk * 32 + ((lane >> 4) << 3) + i;
            p[idx] = f2bf((n < 90 && k < 90) ? W_sync[k * 90 + n] : 0.f);
        }
    } else if (blk == 133) {               // agF
        unsigned short* p = (unsigned short*)(ws + OFF_AGF);
        for (int idx = tid; idx < 9216; idx += 256) {
            const int i = idx & 7, lane = (idx >> 3) & 63;
            const int rest = idx >> 9, kk = rest % 3, nt = rest / 3;
            const int n = nt * 16 + (lane & 15);
            const int k = kk * 32 + ((lane >> 4) << 3) + i;
            p[idx] = f2bf((n < 90 && k < 90) ? W_agg[k * 90 + n] : 0.f);
        }
    } else if (blk < 136) {                // wiF
        unsigned short* p = (unsigned short*)(ws + OFF_WIF);
        const int i0 = (blk - 134) * 13056, i1 = i0 + 13056;
        for (int idx = i0 + tid; idx < i1; idx += 256) {
            const int i = idx & 7, lane = (idx >> 3) & 63;
            const int rest = idx >> 9, kk = rest % 3, nt = rest / 3;
            const int n = nt * 16 + (lane & 15);
            const int k = kk * 32 + ((lane >> 4) << 3) + i;
            p[idx] = f2bf((n < 270 && k < 90) ? Wi_rnn[k * 270 + n] : 0.f);
        }
    } else if (blk < 138) {                // wisF
        unsigned short* p = (unsigned short*)(ws + OFF_WISF);
        const int i0 = (blk - 136) * 13056, i1 = i0 + 13056;
        for (int idx = i0 + tid; idx < i1; idx += 256) {
            const int i = idx & 7, lane = (idx >> 3) & 63;
            const int rest = idx >> 9, kk = rest % 3, nt = rest / 3;
            const int n = nt * 16 + (lane & 15);
            const int k = kk * 32 + ((lane >> 4) << 3) + i;
            p[idx] = f2bf((n < 270 && k < 90) ? Wi_self[k * 270 + n] : 0.f);
        }
    } else if (blk < 140) {                // whsF
        unsigned short* p = (unsigned short*)(ws + OFF_WHSF);
        const int i0 = (blk - 138) * 13056, i1 = i0 + 13056;
        for (int idx = i0 + tid; idx < i1; idx += 256) {
            const int i = idx & 7, lane = (idx >> 3) & 63;
            const int rest = idx >> 9, kk = rest % 3, nt = rest / 3;
            const int n = nt * 16 + (lane & 15);
            const int k = kk * 32 + ((lane >> 4) << 3) + i;
            p[idx] = f2bf((n < 270 && k < 90) ? Wh_self[k * 270 + n] : 0.f);
        }
    } else if (blk == 140) {               // symF
        unsigned short* p = (unsigned short*)(ws + OFF_SYMF);
        for (int idx = tid; idx < 9216; idx += 256) {
            const int i = idx & 7, lane = (idx >> 3) & 63;
            const int rest = idx >> 9, kk = rest % 3, nt = rest / 3;
            const int n = nt * 16 + (lane & 15);
            const int k = kk * 32 + ((lane >> 4) << 3) + i;
            p[idx] = f2bf((n < 90 && k < 90) ? W_sync[(90 + k) * 90 + n] : 0.f);
        }
    } else {                               // wprF (K=192 padded)
        unsigned short* p = (unsigned short*)(ws + OFF_WPRF);
        for (int idx = tid; idx < 18432; idx += 256) {
            const int i = idx & 7, lane = (idx >> 3) & 63;
            const int rest = idx >> 9, kk = rest % 6, nt = rest / 6;
            const int n = nt * 16 + (lane & 15);
            const int k = kk * 32 + ((lane >> 4) << 3) + i;
            p[idx] = f2bf((n < 90 && k < 180) ? W_prop[k * 90 + n] : 0.f);
        }
    }
}

// ============ per-step kernel: 256 blocks x 512 thr, TIL=64 ============
__global__ __launch_bounds__(512, 1) void skt_step(
    const int* __restrict__ qs, const int* __restrict__ as_,
    const float* __restrict__ response_emb, const float* __restrict__ concept_emb,
    const float* __restrict__ nb_adj, const float* __restrict__ succ_adj,
    const float* __restrict__ bi_self, const float* __restrict__ bh_self,
    const float* __restrict__ bi_rnn, const float* __restrict__ bh_rnn,
    const float* __restrict__ b_agg, const float* __restrict__ b_prop,
    const float* __restrict__ W_out, const float* __restrict__ b_out,
    float* __restrict__ ws, const float* __restrict__ stIn, float* __restrict__ stOut,
    float* __restrict__ out, int t) {
    __shared__ alignas(16) float hR[TIL * 100];
    __shared__ alignas(16) float hnb[NBMAX * 96];
    __shared__ alignas(16) float rfd[NBMAX * 92];
    __shared__ alignas(16) float giL[SLOTS * 273];
    __shared__ alignas(16) float actb[SLOTS * 96], infb[SLOTS * 96];
    __shared__ alignas(16) float giA[272], ghA[272];
    __shared__ alignas(16) float gi0L[273], biL[273], bhL[272];
    __shared__ alignas(16) float re[96], ssv[96], ceq[96];
    __shared__ alignas(16) float nsvW[6][96], xpW[6][192];
    __shared__ alignas(16) float nsyL[96], pvL[96], baggL[96];
    __shared__ float nbw[NBMAX];
    __shared__ int nblist[NBMAX];
    __shared__ float nbvL[TIL], svL[TIL];
    __shared__ int rowslotS[TIL], listS[TIL];
    __shared__ int nactS, nnbS;

    const int tid = threadIdx.x;
    const int bb = blockIdx.x >> 3;
    const int k0 = (blockIdx.x & 7) * TIL;
    const int q = qs[bb * NT + t];
    const int a = as_[bb * NT + t];
    const bool owner = (q >= k0 && q < k0 + TIL);

    const int w8 = tid >> 6, lane = tid & 63;
    const int lr = lane & 15, lh = lane >> 4;
    const int rt = w8 & 3, cg = w8 >> 2;
    const bf16x8 z8 = {0, 0, 0, 0, 0, 0, 0, 0};

    const unsigned short* whtF = (const unsigned short*)(ws + OFF_WHTF);
    const unsigned short* syF = (const unsigned short*)(ws + OFF_SYF);
    const unsigned short* agF = (const unsigned short*)(ws + OFF_AGF);
    const unsigned short* wiF = (const unsigned short*)(ws + OFF_WIF);
    const unsigned short* wisF = (const unsigned short*)(ws + OFF_WISF);
    const unsigned short* whsF = (const unsigned short*)(ws + OFF_WHSF);
    const unsigned short* symF = (const unsigned short*)(ws + OFF_SYMF);
    const unsigned short* wprF = (const unsigned short*)(ws + OFF_WPRF);

    // ================= B0: stage + scans + out(t-1) =================
    if (tid < 384) {                     // hR 64 x 50 float2 (cols 90..99 zero)
        for (int idx = tid; idx < TIL * 50; idx += 384) {
            const int row = idx / 50, c2 = idx - row * 50;
            float2 v = make_float2(0.f, 0.f);
            if (c2 < 45)
                v = ((const float2*)(stIn + ((size_t)(bb * KU + k0 + row)) * 90))[c2];
            *(float2*)&hR[row * 100 + 2 * c2] = v;
        }
    } else if (tid < 448) {              // wave 6: active-row scan
        const int l = tid - 384;
        const int kg = k0 + l;
        const float nv = nb_adj[(size_t)q * KU + kg];
        const float sv = succ_adj[(size_t)q * KU + kg];
        nbvL[l] = nv; svL[l] = sv;
        const bool act = (nv != 0.f) || (sv != 0.f) || (kg == q);
        const unsigned long long mb = __ballot(act);
        const int rank = (int)__popcll(mb & ((1ull << l) - 1ull));
        rowslotS[l] = act ? rank : -1;
        if (act) listS[rank] = l;
        if (l == 0) nactS = (int)__popcll(mb);
    } else {                             // wave 7: neighbor scan of q
        const int l = tid - 448;
        int base = 0;
        for (int ch = 0; ch < 8; ++ch) {
            const int kp = ch * 64 + l;
            const float nv = nb_adj[(size_t)q * KU + kp];
            const unsigned long long mb = __ballot(nv != 0.f);
            const int idx = base + (int)__popcll(mb & ((1ull << l) - 1ull));
            if (nv != 0.f && idx < NBMAX) { nblist[idx] = kp; nbw[idx] = nv; }
            base += (int)__popcll(mb);
        }
        if (l == 0) nnbS = (base < NBMAX) ? base : NBMAX;
    }
    for (int j = tid; j < 270; j += 512) {
        if (j < 90) re[j] = response_emb[(size_t)a * 90 + j];
        else if (j < 180) ssv[j - 90] = stIn[((size_t)(bb * KU + q)) * 90 + (j - 90)];
        else ceq[j - 180] = concept_emb[(size_t)q * 90 + (j - 180)];
    }
    for (int c = tid; c < 273; c += 512) {
        gi0L[c] = (c < 272) ? ws[OFF_GI0 + c] : 0.f;
        biL[c] = (c < 270) ? bi_rnn[c] : 0.f;
        if (c < 272) bhL[c] = (c < 270) ? bh_rnn[c] : 0.f;
    }
    if (tid < 96) {
        baggL[tid] = (tid < 90) ? b_agg[tid] : 0.f;
        if (tid >= 90) { re[tid] = 0.f; ssv[tid] = 0.f; ceq[tid] = 0.f; }
    } else if (tid < 132) {
        nsvW[(tid - 96) / 6][90 + (tid - 96) % 6] = 0.f;
    } else if (tid < 204) {
        xpW[(tid - 132) / 12][180 + (tid - 132) % 12] = 0.f;
    }
    for (int j2 = tid; j2 < SLOTS * 6 * 2; j2 += 512) {
        const int half = j2 >= SLOTS * 6;
        const int jj = half ? j2 - SLOTS * 6 : j2;
        (half ? infb : actb)[(jj / 6) * 96 + 90 + (jj % 6)] = 0.f;
    }
    // out(t-1) from stIn (free: overlapped with staging)
    if (t > 0) {
        const int row = tid >> 3, j = tid & 7;
        const float* sp = stIn + ((size_t)(bb * KU + k0 + row)) * 90;
        float p = 0.f;
#pragma unroll
        for (int mm = 0; mm < 12; ++mm) {
            const int m = j * 12 + mm;
            if (m < 90) p += sp[m] * W_out[m];
        }
#pragma unroll
        for (int o = 1; o < 8; o <<= 1) p += __shfl_xor(p, o);
        if (j == 0)
            out[(size_t)(t - 1) * NB * KU + (size_t)bb * KU + k0 + row] = sigf(p + b_out[0]);
    }
    __syncthreads();   // ---- barrier 1 ----

    // ================= B1: owner hnb gather | self-GRU MFMA | gh GEMM =================
    if (owner) {
        const int nnb = nnbS;
        for (int i = tid; i < nnb * 48; i += 512) {
            const int j = i / 48, c2 = i - j * 48;
            float2 v = make_float2(0.f, 0.f);
            if (c2 < 45)
                v = ((const float2*)(stIn + ((size_t)(bb * KU + nblist[j])) * 90))[c2];
            *(float2*)&hnb[j * 96 + 2 * c2] = v;
        }
    }
    {   // self-GRU matvecs via M=2 MFMA: A row0=re, row1=ssv
        bf16x8 af[3];
#pragma unroll
        for (int kk = 0; kk < 3; ++kk)
            af[kk] = (lr == 0) ? cvt8(&re[kk * 32 + lh * 8])
                   : ((lr == 1) ? cvt8(&ssv[kk * 32 + lh * 8]) : z8);
        for (int nt = w8; nt < 17; nt += 8) {
            const f32x4 dwi = mm3(af, wisF + (size_t)nt * 1536 + lane * 8);
            const f32x4 dwh = mm3(af, whsF + (size_t)nt * 1536 + lane * 8);
            if (lh == 0) {
                const int c = nt * 16 + lr;
                if (c < 270) { giA[c] = bi_self[c] + dwi[0]; ghA[c] = bh_self[c] + dwh[1]; }
            }
        }
    }
    // gh GEMM: A = own hR rows, B = whtF
    f32x4 acc[3][3];
#pragma unroll
    for (int g = 0; g < 3; ++g)
#pragma unroll
        for (int ct = 0; ct < 3; ++ct) acc[g][ct] = f32x4{0.f, 0.f, 0.f, 0.f};
    {
        bf16x8 afr[3];
        const float* ar = &hR[(rt * 16 + lr) * 100];
#pragma unroll
        for (int kk = 0; kk < 3; ++kk) afr[kk] = cvt8(ar + kk * 32 + lh * 8);
#pragma unroll
        for (int g = 0; g < 3; ++g) {
#pragma unroll
            for (int ct = 0; ct < 3; ++ct) {
                const int nb = cg * 3 + ct;
                const unsigned short* bp = whtF + (size_t)(g * 6 + nb) * 1536 + lane * 8;
                acc[g][ct] = __builtin_amdgcn_mfma_f32_16x16x32_bf16(afr[0], *(const bf16x8*)(bp), acc[g][ct], 0, 0, 0);
                acc[g][ct] = __builtin_amdgcn_mfma_f32_16x16x32_bf16(afr[1], *(const bf16x8*)(bp + 512), acc[g][ct], 0, 0, 0);
                acc[g][ct] = __builtin_amdgcn_mfma_f32_16x16x32_bf16(afr[2], *(const bf16x8*)(bp + 1024), acc[g][ct], 0, 0, 0);
            }
        }
    }
    __syncthreads();   // ---- barrier 2 ----

    // ================= B2': nsv/xprop + nsync/pvec (w<6) | rfd (w6-7, owner)
    //                   + INACTIVE-ROW GATES + stores (all waves, overlap C1-C3) =========
    const int m6 = w8 * 16 + lr;
    if (w8 < 6) {
        {   // wave-local nsv / xprop (redundant per wave; identical f32 math)
            const int l1 = lane, l2 = lane + 64;
            if (l1 < 90) {
                const float r = sigf(giA[l1] + ghA[l1]);
                const float z = sigf(giA[90 + l1] + ghA[90 + l1]);
                const float g = tanhf_(giA[180 + l1] + r * ghA[180 + l1]);
                const float ns = (1.f - z) * g + z * ssv[l1];
                nsvW[w8][l1] = ns;
                xpW[w8][l1] = ns - ssv[l1];
                xpW[w8][90 + l1] = ceq[l1];
            }
            if (l2 < 90) {
                const float r = sigf(giA[l2] + ghA[l2]);
                const float z = sigf(giA[90 + l2] + ghA[90 + l2]);
                const float g = tanhf_(giA[180 + l2] + r * ghA[180 + l2]);
                const float ns = (1.f - z) * g + z * ssv[l2];
                nsvW[w8][l2] = ns;
                xpW[w8][l2] = ns - ssv[l2];
                xpW[w8][90 + l2] = ceq[l2];
            }
        }
        {   // nsync (M=1)
            bf16x8 af[3];
#pragma unroll
            for (int kk = 0; kk < 3; ++kk)
                af[kk] = (lr == 0) ? cvt8(&nsvW[w8][kk * 32 + lh * 8]) : z8;
            const f32x4 d = mm3(af, symF + (size_t)w8 * 1536 + lane * 8);
            if (lh == 0) nsyL[m6] = (m6 < 90) ? d[0] : 0.f;
        }
        {   // pvec (M=1, K=192)
            f32x4 d = f32x4{0.f, 0.f, 0.f, 0.f};
            const unsigned short* bp = wprF + (size_t)w8 * 3072 + lane * 8;
#pragma unroll
            for (int kk = 0; kk < 6; ++kk) {
                const bf16x8 av = (lr == 0) ? cvt8(&xpW[w8][kk * 32 + lh * 8]) : z8;
                d = __builtin_amdgcn_mfma_f32_16x16x32_bf16(av, *(const bf16x8*)(bp + kk * 512), d, 0, 0, 0);
            }
            if (lh == 0) pvL[m6] = (m6 < 90) ? fmaxf(b_prop[m6] + d[0], 0.f) : 0.f;
        }
    } else if (owner) {
        // rfd MFMA on waves 6-7 (independent of nsync)
        const int nnb = nnbS;
        const int pairs = ((nnb + 15) >> 4) * 6;
        for (int p = w8 - 6; p < pairs; p += 2) {
            const int mt = p / 6, nt = p - mt * 6;
            bf16x8 af[3];
            const int jrow = mt * 16 + lr;
            if (jrow < nnb) {
                const float* rp = &hnb[jrow * 96];
#pragma unroll
                for (int kk = 0; kk < 3; ++kk) af[kk] = cvt8(rp + kk * 32 + lh * 8);
            } else { af[0] = z8; af[1] = z8; af[2] = z8; }
            const f32x4 d = mm3(af, syF + (size_t)nt * 1536 + lane * 8);
#pragma unroll
            for (int r4 = 0; r4 < 4; ++r4) {
                const int j = mt * 16 + lh * 4 + r4;
                const int m = nt * 16 + lr;
                if (j < nnb && m < 90)
                    rfd[j * 92 + m] = d[r4] + ws[OFF_CEB + (size_t)nblist[j] * 90 + m];
            }
        }
    }
    // inactive-row gates (gi0L; ~96% of rows) — stores overlap the C phases
#pragma unroll
    for (int ct = 0; ct < 3; ++ct) {
        const int m = cg * 48 + ct * 16 + lr;
        if (m < 90) {
            const float bhr = bhL[m], bhz = bhL[90 + m], bhg = bhL[180 + m];
#pragma unroll
            for (int r4 = 0; r4 < 4; ++r4) {
                const int row = rt * 16 + 4 * lh + r4;
                if (rowslotS[row] >= 0) continue;
                const float rg = sigf(gi0L[m] + acc[0][ct][r4] + bhr);
                const float zg = sigf(gi0L[90 + m] + acc[1][ct][r4] + bhz);
                const float gg = tanhf_(gi0L[180 + m] + rg * (acc[2][ct][r4] + bhg));
                const float hold = hR[row * 100 + m];
                const float hn = (1.f - zg) * gg + zg * hold;
                stOut[((size_t)(bb * KU + k0 + row)) * 90 + m] = hn;
            }
        }
    }
    __syncthreads();   // ---- barrier 3 ----

    // ================= C: MFMA chains + gates for ACTIVE rows only ==========
    const int nact = nactS;
    const int npass0 = (nact + SLOTS - 1) / SLOTS;
    const int npass = (npass0 > 0) ? npass0 : 1;
    for (int pass = 0; pass < npass; ++pass) {
        const int e0p = pass * SLOTS;
        int e1p = e0p + SLOTS; if (e1p > nact) e1p = nact;
        const int na = e1p - e0p;

        // C1: act
        if (na > 0 && w8 < 6) {
            const int nt = w8;
            bf16x8 af[3];
            if (lr < na) {
                const float* rp = &hR[listS[e0p + lr] * 100];
#pragma unroll
                for (int kk = 0; kk < 3; ++kk) af[kk] = cvt8(rp + kk * 32 + lh * 8);
            } else { af[0] = z8; af[1] = z8; af[2] = z8; }
            const f32x4 d = mm3(af, syF + (size_t)nt * 1536 + lane * 8);
            const int m = nt * 16 + lr;
            if (m < 90) {
#pragma unroll
                for (int r4 = 0; r4 < 4; ++r4) {
                    const int slot = lh * 4 + r4;
                    if (slot >= na) continue;
                    const int r = listS[e0p + slot];
                    const float nv = nbvL[r], sv = svL[r];
                    float s = 0.f;
                    if (nv != 0.f)
                        s = nv * fmaxf(nsyL[m] + ws[OFF_CEB + (size_t)(k0 + r) * 90 + m] + d[r4], 0.f);
                    if (k0 + r == q) {
                        const int nnb = nnbS;
                        const float nm = nsyL[m];
                        for (int j = 0; j < nnb; ++j)
                            s += nbw[j] * fmaxf(nm + rfd[j * 92 + m], 0.f);
                    }
                    actb[slot * 96 + m] = 0.5f * s + 0.5f * sv * pvL[m];
                }
            }
        }
        __syncthreads();   // ---- barrier 4 ----

        // C2: inf
        if (na > 0 && w8 < 6) {
            const int nt = w8;
            bf16x8 af[3];
            if (lr < na) {
                const float* rp = &actb[lr * 96];
#pragma unroll
                for (int kk = 0; kk < 3; ++kk) af[kk] = cvt8(rp + kk * 32 + lh * 8);
            } else { af[0] = z8; af[1] = z8; af[2] = z8; }
            const f32x4 d = mm3(af, agF + (size_t)nt * 1536 + lane * 8);
            const int m = nt * 16 + lr;
            if (m < 90) {
#pragma unroll
                for (int r4 = 0; r4 < 4; ++r4) {
                    const int slot = lh * 4 + r4;
                    if (slot < na) infb[slot * 96 + m] = fmaxf(baggL[m] + d[r4], 0.f);
                }
            }
        }
        __syncthreads();   // ---- barrier 5 ----

        // C3: gi
        if (na > 0) {
            bf16x8 af[3];
            if (lr < na) {
                const float* rp = &infb[lr * 96];
#pragma unroll
                for (int kk = 0; kk < 3; ++kk) af[kk] = cvt8(rp + kk * 32 + lh * 8);
            } else { af[0] = z8; af[1] = z8; af[2] = z8; }
            for (int nt = w8; nt < 17; nt += 8) {
                const f32x4 d = mm3(af, wiF + (size_t)nt * 1536 + lane * 8);
                const int c = nt * 16 + lr;
                if (c < 270) {
#pragma unroll
                    for (int r4 = 0; r4 < 4; ++r4) {
                        const int slot = lh * 4 + r4;
                        if (slot < na) giL[slot * 273 + c] = biL[c] + d[r4];
                    }
                }
            }
        }
        __syncthreads();   // ---- barrier 6 ----

        // C4: gates for ACTIVE rows of this pass only (tiny tail)
#pragma unroll
        for (int ct = 0; ct < 3; ++ct) {
            const int m = cg * 48 + ct * 16 + lr;
            if (m < 90) {
                const float bhr = bhL[m], bhz = bhL[90 + m], bhg = bhL[180 + m];
#pragma unroll
                for (int r4 = 0; r4 < 4; ++r4) {
                    const int row = rt * 16 + 4 * lh + r4;
                    const int sraw = rowslotS[row];
                    if (sraw < e0p || sraw >= e1p) continue;   // active rows of this pass
                    const float* gs = &giL[(sraw - e0p) * 273];
                    const float rg = sigf(gs[m] + acc[0][ct][r4] + bhr);
                    const float zg = sigf(gs[90 + m] + acc[1][ct][r4] + bhz);
                    const float gg = tanhf_(gs[180 + m] + rg * (acc[2][ct][r4] + bhg));
                    const float hold = hR[row * 100 + m];
                    const float hn = (1.f - zg) * gg + zg * hold;
                    stOut[((size_t)(bb * KU + k0 + row)) * 90 + m] = hn;
                }
            }
        }
        if (pass + 1 < npass) __syncthreads();
    }
}

// ============ finalize: out[NT-1] from final states ============
__global__ __launch_bounds__(512, 1) void skt_final(
    const float* __restrict__ stFinal, const float* __restrict__ W_out,
    const float* __restrict__ b_out, float* __restrict__ out) {
    const int tid = threadIdx.x;
    const int bb = blockIdx.x >> 3;
    const int k0 = (blockIdx.x & 7) * TIL;
    const int row = tid >> 3, j = tid & 7;
    const float* sp = stFinal + ((size_t)(bb * KU + k0 + row)) * 90;
    float p = 0.f;
#pragma unroll
    for (int mm = 0; mm < 12; ++mm) {
        const int m = j * 12 + mm;
        if (m < 90) p += sp[m] * W_out[m];
    }
#pragma unroll
    for (int o = 1; o < 8; o <<= 1) p += __shfl_xor(p, o);
    if (j == 0)
        out[(size_t)(NT - 1) * NB * KU + (size_t)bb * KU + k0 + row] = sigf(p + b_out[0]);
}

extern "C" void kernel_launch(void* const* d_in, const int* in_sizes, int n_in,
                              void* d_out, int out_size, void* d_ws, size_t ws_size,
                              hipStream_t stream) {
    const int* questions = (const int*)d_in[0];
    const int* answers = (const int*)d_in[1];
    const float* response_emb = (const float*)d_in[2];
    const float* concept_emb = (const float*)d_in[3];
    const float* nb_adj = (const float*)d_in[4];
    const float* succ_adj = (const float*)d_in[5];
    const float* Wi_self = (const float*)d_in[6];
    const float* Wh_self = (const float*)d_in[7];
    const float* bi_self = (const float*)d_in[8];
    const float* bh_self = (const float*)d_in[9];
    const float* Wi_rnn = (const float*)d_in[10];
    const float* Wh_rnn = (const float*)d_in[11];
    const float* bi_rnn = (const float*)d_in[12];
    const float* bh_rnn = (const float*)d_in[13];
    const float* W_sync = (const float*)d_in[14];
    const float* b_sync = (const float*)d_in[15];
    const float* W_prop = (const float*)d_in[16];
    const float* b_prop = (const float*)d_in[17];
    const float* W_agg = (const float*)d_in[18];
    const float* b_agg = (const float*)d_in[19];
    const float* W_out = (const float*)d_in[20];
    const float* b_out = (const float*)d_in[21];

    float* out = (float*)d_out;
    float* stFinal = out + (size_t)NT * NB * KU;   // states region of d_out
    float* ws = (float*)d_ws;

    hipMemsetAsync(stFinal, 0, (size_t)NB * KU * 90 * sizeof(float), stream);
    skt_prep<<<142, 256, 0, stream>>>(concept_emb, W_sync, b_sync, Wi_rnn, Wh_rnn,
                                      Wi_self, Wh_self, W_prop, bi_rnn, b_agg, W_agg, ws);
    for (int t = 0; t < NT; ++t) {
        const float* sin = (t & 1) ? ws : stFinal;
        float* sout = (t & 1) ? stFinal : ws;
        skt_step<<<NB * 8, 512, 0, stream>>>(
            questions, answers, response_emb, concept_emb, nb_adj, succ_adj,
            bi_self, bh_self, bi_rnn, bh_rnn, b_agg, b_prop, W_out, b_out,
            ws, sin, sout, out, t);
    }
    skt_final<<<NB * 8, 512, 0, stream>>>(stFinal, W_out, b_out, out);
}

// Round 17
// 1476.087 us; speedup vs baseline: 1.0771x; 1.0771x over previous
//
#include <hip/hip_runtime.h>

#define KU 512
#define NB 32
#define NT 64
#define TIL 64
#define SLOTS 16
#define NBMAX 40

// ---- ws float offsets ----
#define N_PONG   (KU * NB * 90)
#define OFF_CEB  (N_PONG)                    // ce_sync+b_sync [512][90] f32
#define OFF_GI0  (OFF_CEB + KU * 90)         // gi0 [272] f32
#define OFF_WHTF (OFF_GI0 + 288)             // us[3][6][3][64][8] Wh       (27648 us)
#define OFF_SYF  (OFF_WHTF + 13824)          // us[6][3][64][8]    Wsync_lo (9216 us)
#define OFF_AGF  (OFF_SYF + 4608)            // us[6][3][64][8]    W_agg    (9216 us)
#define OFF_WIF  (OFF_AGF + 4608)            // us[17][3][64][8]   Wi_rnn   (26112 us)
#define OFF_WISF (OFF_WIF + 13056)           // us[17][3][64][8]   Wi_self  (26112 us)
#define OFF_WHSF (OFF_WISF + 13056)          // us[17][3][64][8]   Wh_self  (26112 us)
#define OFF_SYMF (OFF_WHSF + 13056)          // us[6][3][64][8]    Wsync_mid(9216 us)
#define OFF_WPRF (OFF_SYMF + 4608)           // us[6][6][64][8]    W_prop   (18432 us)

typedef short bf16x8 __attribute__((ext_vector_type(8)));
typedef float f32x4 __attribute__((ext_vector_type(4)));

__device__ __forceinline__ float sigf(float x) { return 1.0f / (1.0f + __expf(-x)); }
__device__ __forceinline__ float tanhf_(float x) {
    float e = __expf(2.0f * x);
    return 1.0f - 2.0f / (e + 1.0f);
}
__device__ __forceinline__ unsigned short f2bf(float f) {
    union { float f; unsigned u; } v; v.f = f;
    unsigned r = v.u + 0x7FFFu + ((v.u >> 16) & 1u);
    return (unsigned short)(r >> 16);
}
__device__ __forceinline__ bf16x8 cvt8(const float* p) {
    const float4 a0 = *(const float4*)p;
    const float4 a1 = *(const float4*)(p + 4);
    union { bf16x8 v; unsigned short u[8]; } fr;
    fr.u[0] = f2bf(a0.x); fr.u[1] = f2bf(a0.y); fr.u[2] = f2bf(a0.z); fr.u[3] = f2bf(a0.w);
    fr.u[4] = f2bf(a1.x); fr.u[5] = f2bf(a1.y); fr.u[6] = f2bf(a1.z); fr.u[7] = f2bf(a1.w);
    return fr.v;
}
__device__ __forceinline__ f32x4 mm3(const bf16x8* af, const unsigned short* bp) {
    f32x4 d = f32x4{0.f, 0.f, 0.f, 0.f};
    d = __builtin_amdgcn_mfma_f32_16x16x32_bf16(af[0], *(const bf16x8*)(bp), d, 0, 0, 0);
    d = __builtin_amdgcn_mfma_f32_16x16x32_bf16(af[1], *(const bf16x8*)(bp + 512), d, 0, 0, 0);
    d = __builtin_amdgcn_mfma_f32_16x16x32_bf16(af[2], *(const bf16x8*)(bp + 1024), d, 0, 0, 0);
    return d;
}

// ============ prep: ce_sync + gi0 + all bf16 weight fragments (once) ============
__global__ void skt_prep(const float* __restrict__ concept_emb, const float* __restrict__ W_sync,
                         const float* __restrict__ b_sync, const float* __restrict__ Wi_rnn,
                         const float* __restrict__ Wh_rnn, const float* __restrict__ Wi_self,
                         const float* __restrict__ Wh_self, const float* __restrict__ W_prop,
                         const float* __restrict__ bi_rnn, const float* __restrict__ b_agg,
                         const float* __restrict__ W_agg, float* __restrict__ ws) {
    const int blk = blockIdx.x, tid = threadIdx.x;
    if (blk < 128) {                       // ceb[512][90]
        for (int rr = 0; rr < 4; ++rr) {
            const int k = blk * 4 + rr;
            if (tid < 90) {
                float acc = b_sync[tid];
                for (int kk = 0; kk < 90; ++kk)
                    acc += concept_emb[k * 90 + kk] * W_sync[(180 + kk) * 90 + tid];
                ws[OFF_CEB + k * 90 + tid] = acc;
            }
        }
    } else if (blk < 131) {                // whtF
        const int g = blk - 128;
        unsigned short* p = (unsigned short*)(ws + OFF_WHTF);
        for (int idx = tid; idx < 9216; idx += 256) {
            const int i = idx & 7, lane = (idx >> 3) & 63;
            const int rest = idx >> 9, kk = rest % 3, nb = rest / 3;
            const int n = nb * 16 + (lane & 15);
            const int k = kk * 32 + ((lane >> 4) << 3) + i;
            p[(size_t)g * 9216 + idx] = f2bf((n < 90 && k < 90) ? Wh_rnn[k * 270 + g * 90 + n] : 0.f);
        }
    } else if (blk == 131) {               // gi0
        for (int c = tid; c < 272; c += 256) {
            float acc = 0.f;
            if (c < 270) {
                acc = bi_rnn[c];
                for (int kk = 0; kk < 90; ++kk)
                    acc += fmaxf(b_agg[kk], 0.f) * Wi_rnn[kk * 270 + c];
            }
            ws[OFF_GI0 + c] = acc;
        }
    } else if (blk == 132) {               // syF
        unsigned short* p = (unsigned short*)(ws + OFF_SYF);
        for (int idx = tid; idx < 9216; idx += 256) {
            const int i = idx & 7, lane = (idx >> 3) & 63;
            const int rest = idx >> 9, kk = rest % 3, nt = rest / 3;
            const int n = nt * 16 + (lane & 15);
            const int k = kk * 32 + ((lane >> 4) << 3) + i;
            p[idx] = f2bf((n < 90 && k < 90) ? W_sync[k * 90 + n] : 0.f);
        }
    } else if (blk == 133) {               // agF
        unsigned short* p = (unsigned short*)(ws + OFF_AGF);
        for (int idx = tid; idx < 9216; idx += 256) {
            const int i = idx & 7, lane = (idx >> 3) & 63;
            const int rest = idx >> 9, kk = rest % 3, nt = rest / 3;
            const int n = nt * 16 + (lane & 15);
            const int k = kk * 32 + ((lane >> 4) << 3) + i;
            p[idx] = f2bf((n < 90 && k < 90) ? W_agg[k * 90 + n] : 0.f);
        }
    } else if (blk < 136) {                // wiF
        unsigned short* p = (unsigned short*)(ws + OFF_WIF);
        const int i0 = (blk - 134) * 13056, i1 = i0 + 13056;
        for (int idx = i0 + tid; idx < i1; idx += 256) {
            const int i = idx & 7, lane = (idx >> 3) & 63;
            const int rest = idx >> 9, kk = rest % 3, nt = rest / 3;
            const int n = nt * 16 + (lane & 15);
            const int k = kk * 32 + ((lane >> 4) << 3) + i;
            p[idx] = f2bf((n < 270 && k < 90) ? Wi_rnn[k * 270 + n] : 0.f);
        }
    } else if (blk < 138) {                // wisF
        unsigned short* p = (unsigned short*)(ws + OFF_WISF);
        const int i0 = (blk - 136) * 13056, i1 = i0 + 13056;
        for (int idx = i0 + tid; idx < i1; idx += 256) {
            const int i = idx & 7, lane = (idx >> 3) & 63;
            const int rest = idx >> 9, kk = rest % 3, nt = rest / 3;
            const int n = nt * 16 + (lane & 15);
            const int k = kk * 32 + ((lane >> 4) << 3) + i;
            p[idx] = f2bf((n < 270 && k < 90) ? Wi_self[k * 270 + n] : 0.f);
        }
    } else if (blk < 140) {                // whsF
        unsigned short* p = (unsigned short*)(ws + OFF_WHSF);
        const int i0 = (blk - 138) * 13056, i1 = i0 + 13056;
        for (int idx = i0 + tid; idx < i1; idx += 256) {
            const int i = idx & 7, lane = (idx >> 3) & 63;
            const int rest = idx >> 9, kk = rest % 3, nt = rest / 3;
            const int n = nt * 16 + (lane & 15);
            const int k = kk * 32 + ((lane >> 4) << 3) + i;
            p[idx] = f2bf((n < 270 && k < 90) ? Wh_self[k * 270 + n] : 0.f);
        }
    } else if (blk == 140) {               // symF
        unsigned short* p = (unsigned short*)(ws + OFF_SYMF);
        for (int idx = tid; idx < 9216; idx += 256) {
            const int i = idx & 7, lane = (idx >> 3) & 63;
            const int rest = idx >> 9, kk = rest % 3, nt = rest / 3;
            const int n = nt * 16 + (lane & 15);
            const int k = kk * 32 + ((lane >> 4) << 3) + i;
            p[idx] = f2bf((n < 90 && k < 90) ? W_sync[(90 + k) * 90 + n] : 0.f);
        }
    } else {                               // wprF (K=192 padded)
        unsigned short* p = (unsigned short*)(ws + OFF_WPRF);
        for (int idx = tid; idx < 18432; idx += 256) {
            const int i = idx & 7, lane = (idx >> 3) & 63;
            const int rest = idx >> 9, kk = rest % 6, nt = rest / 6;
            const int n = nt * 16 + (lane & 15);
            const int k = kk * 32 + ((lane >> 4) << 3) + i;
            p[idx] = f2bf((n < 90 && k < 180) ? W_prop[k * 90 + n] : 0.f);
        }
    }
}

// ============ per-step kernel: 256 blocks x 512 thr, TIL=64, 6 barriers/step ============
__global__ __launch_bounds__(512, 1) void skt_step(
    const int* __restrict__ qs, const int* __restrict__ as_,
    const float* __restrict__ response_emb, const float* __restrict__ concept_emb,
    const float* __restrict__ nb_adj, const float* __restrict__ succ_adj,
    const float* __restrict__ bi_self, const float* __restrict__ bh_self,
    const float* __restrict__ bi_rnn, const float* __restrict__ bh_rnn,
    const float* __restrict__ b_agg, const float* __restrict__ b_prop,
    const float* __restrict__ W_out, const float* __restrict__ b_out,
    float* __restrict__ ws, const float* __restrict__ stIn, float* __restrict__ stOut,
    float* __restrict__ out, int t) {
    __shared__ alignas(16) float hR[TIL * 100];
    __shared__ alignas(16) float hnb[NBMAX * 96];
    __shared__ alignas(16) float rfd[NBMAX * 92];
    __shared__ alignas(16) float giL[SLOTS * 273];
    __shared__ alignas(16) float actb[SLOTS * 96], infb[SLOTS * 96];
    __shared__ alignas(16) float giA[272], ghA[272];
    __shared__ alignas(16) float gi0L[273], biL[273], bhL[272];
    __shared__ alignas(16) float re[96], ssv[96], ceq[96];
    __shared__ alignas(16) float nsvW[6][96], xpW[6][192];
    __shared__ alignas(16) float nsyL[96], pvL[96], baggL[96];
    __shared__ float nbw[NBMAX];
    __shared__ int nblist[NBMAX];
    __shared__ float nbvL[TIL], svL[TIL];
    __shared__ int rowslotS[TIL], listS[TIL];
    __shared__ int nactS, nnbS;

    const int tid = threadIdx.x;
    const int bb = blockIdx.x >> 3;
    const int k0 = (blockIdx.x & 7) * TIL;
    const int q = qs[bb * NT + t];
    const int a = as_[bb * NT + t];
    const bool owner = (q >= k0 && q < k0 + TIL);
    const bool havePrev = (t > 0);       // t==0: states are implicitly zero (no global read)

    const int w8 = tid >> 6, lane = tid & 63;
    const int lr = lane & 15, lh = lane >> 4;
    const int rt = w8 & 3, cg = w8 >> 2;
    const bf16x8 z8 = {0, 0, 0, 0, 0, 0, 0, 0};

    const unsigned short* whtF = (const unsigned short*)(ws + OFF_WHTF);
    const unsigned short* syF = (const unsigned short*)(ws + OFF_SYF);
    const unsigned short* agF = (const unsigned short*)(ws + OFF_AGF);
    const unsigned short* wiF = (const unsigned short*)(ws + OFF_WIF);
    const unsigned short* wisF = (const unsigned short*)(ws + OFF_WISF);
    const unsigned short* whsF = (const unsigned short*)(ws + OFF_WHSF);
    const unsigned short* symF = (const unsigned short*)(ws + OFF_SYMF);
    const unsigned short* wprF = (const unsigned short*)(ws + OFF_WPRF);

    // ================= B0: stage + scans + out(t-1) =================
    if (tid < 384) {                     // hR 64 x 50 float2 (cols 90..99 zero)
        for (int idx = tid; idx < TIL * 50; idx += 384) {
            const int row = idx / 50, c2 = idx - row * 50;
            float2 v = make_float2(0.f, 0.f);
            if (c2 < 45 && havePrev)
                v = ((const float2*)(stIn + ((size_t)(bb * KU + k0 + row)) * 90))[c2];
            *(float2*)&hR[row * 100 + 2 * c2] = v;
        }
    } else if (tid < 448) {              // wave 6: active-row scan
        const int l = tid - 384;
        const int kg = k0 + l;
        const float nv = nb_adj[(size_t)q * KU + kg];
        const float sv = succ_adj[(size_t)q * KU + kg];
        nbvL[l] = nv; svL[l] = sv;
        const bool act = (nv != 0.f) || (sv != 0.f) || (kg == q);
        const unsigned long long mb = __ballot(act);
        const int rank = (int)__popcll(mb & ((1ull << l) - 1ull));
        rowslotS[l] = act ? rank : -1;
        if (act) listS[rank] = l;
        if (l == 0) nactS = (int)__popcll(mb);
    } else {                             // wave 7: neighbor scan of q
        const int l = tid - 448;
        int base = 0;
        for (int ch = 0; ch < 8; ++ch) {
            const int kp = ch * 64 + l;
            const float nv = nb_adj[(size_t)q * KU + kp];
            const unsigned long long mb = __ballot(nv != 0.f);
            const int idx = base + (int)__popcll(mb & ((1ull << l) - 1ull));
            if (nv != 0.f && idx < NBMAX) { nblist[idx] = kp; nbw[idx] = nv; }
            base += (int)__popcll(mb);
        }
        if (l == 0) nnbS = (base < NBMAX) ? base : NBMAX;
    }
    for (int j = tid; j < 270; j += 512) {
        if (j < 90) re[j] = response_emb[(size_t)a * 90 + j];
        else if (j < 180) ssv[j - 90] = havePrev ? stIn[((size_t)(bb * KU + q)) * 90 + (j - 90)] : 0.f;
        else ceq[j - 180] = concept_emb[(size_t)q * 90 + (j - 180)];
    }
    for (int c = tid; c < 273; c += 512) {
        gi0L[c] = (c < 272) ? ws[OFF_GI0 + c] : 0.f;
        biL[c] = (c < 270) ? bi_rnn[c] : 0.f;
        if (c < 272) bhL[c] = (c < 270) ? bh_rnn[c] : 0.f;
    }
    if (tid < 96) {
        baggL[tid] = (tid < 90) ? b_agg[tid] : 0.f;
        if (tid >= 90) { re[tid] = 0.f; ssv[tid] = 0.f; ceq[tid] = 0.f; }
    } else if (tid < 132) {
        nsvW[(tid - 96) / 6][90 + (tid - 96) % 6] = 0.f;
    } else if (tid < 204) {
        xpW[(tid - 132) / 12][180 + (tid - 132) % 12] = 0.f;
    }
    for (int j2 = tid; j2 < SLOTS * 6 * 2; j2 += 512) {
        const int half = j2 >= SLOTS * 6;
        const int jj = half ? j2 - SLOTS * 6 : j2;
        (half ? infb : actb)[(jj / 6) * 96 + 90 + (jj % 6)] = 0.f;
    }
    // out(t-1) from stIn (free: overlapped with staging)
    if (havePrev) {
        const int row = tid >> 3, j = tid & 7;
        const float* sp = stIn + ((size_t)(bb * KU + k0 + row)) * 90;
        float p = 0.f;
#pragma unroll
        for (int mm = 0; mm < 12; ++mm) {
            const int m = j * 12 + mm;
            if (m < 90) p += sp[m] * W_out[m];
        }
#pragma unroll
        for (int o = 1; o < 8; o <<= 1) p += __shfl_xor(p, o);
        if (j == 0)
            out[(size_t)(t - 1) * NB * KU + (size_t)bb * KU + k0 + row] = sigf(p + b_out[0]);
    }
    __syncthreads();   // ---- barrier 1 ----

    // ================= B1: owner hnb gather | self-GRU MFMA | gh GEMM =================
    if (owner) {
        const int nnb = nnbS;
        for (int i = tid; i < nnb * 48; i += 512) {
            const int j = i / 48, c2 = i - j * 48;
            float2 v = make_float2(0.f, 0.f);
            if (c2 < 45 && havePrev)
                v = ((const float2*)(stIn + ((size_t)(bb * KU + nblist[j])) * 90))[c2];
            *(float2*)&hnb[j * 96 + 2 * c2] = v;
        }
    }
    {   // self-GRU matvecs via M=2 MFMA: A row0=re, row1=ssv
        bf16x8 af[3];
#pragma unroll
        for (int kk = 0; kk < 3; ++kk)
            af[kk] = (lr == 0) ? cvt8(&re[kk * 32 + lh * 8])
                   : ((lr == 1) ? cvt8(&ssv[kk * 32 + lh * 8]) : z8);
        for (int nt = w8; nt < 17; nt += 8) {
            const f32x4 dwi = mm3(af, wisF + (size_t)nt * 1536 + lane * 8);
            const f32x4 dwh = mm3(af, whsF + (size_t)nt * 1536 + lane * 8);
            if (lh == 0) {
                const int c = nt * 16 + lr;
                if (c < 270) { giA[c] = bi_self[c] + dwi[0]; ghA[c] = bh_self[c] + dwh[1]; }
            }
        }
    }
    // gh GEMM: A = own hR rows, B = whtF
    f32x4 acc[3][3];
#pragma unroll
    for (int g = 0; g < 3; ++g)
#pragma unroll
        for (int ct = 0; ct < 3; ++ct) acc[g][ct] = f32x4{0.f, 0.f, 0.f, 0.f};
    {
        bf16x8 afr[3];
        const float* ar = &hR[(rt * 16 + lr) * 100];
#pragma unroll
        for (int kk = 0; kk < 3; ++kk) afr[kk] = cvt8(ar + kk * 32 + lh * 8);
#pragma unroll
        for (int g = 0; g < 3; ++g) {
#pragma unroll
            for (int ct = 0; ct < 3; ++ct) {
                const int nb = cg * 3 + ct;
                const unsigned short* bp = whtF + (size_t)(g * 6 + nb) * 1536 + lane * 8;
                acc[g][ct] = __builtin_amdgcn_mfma_f32_16x16x32_bf16(afr[0], *(const bf16x8*)(bp), acc[g][ct], 0, 0, 0);
                acc[g][ct] = __builtin_amdgcn_mfma_f32_16x16x32_bf16(afr[1], *(const bf16x8*)(bp + 512), acc[g][ct], 0, 0, 0);
                acc[g][ct] = __builtin_amdgcn_mfma_f32_16x16x32_bf16(afr[2], *(const bf16x8*)(bp + 1024), acc[g][ct], 0, 0, 0);
            }
        }
    }
    __syncthreads();   // ---- barrier 2 ----

    // ================= B2': nsv/xprop per-wave + nsync/pvec (w<6) | rfd (w6-7, owner) ====
    const int m6 = w8 * 16 + lr;
    if (w8 < 6) {
        {   // wave-local nsv / xprop (redundant per wave; identical f32 math)
            const int l1 = lane, l2 = lane + 64;
            if (l1 < 90) {
                const float r = sigf(giA[l1] + ghA[l1]);
                const float z = sigf(giA[90 + l1] + ghA[90 + l1]);
                const float g = tanhf_(giA[180 + l1] + r * ghA[180 + l1]);
                const float ns = (1.f - z) * g + z * ssv[l1];
                nsvW[w8][l1] = ns;
                xpW[w8][l1] = ns - ssv[l1];
                xpW[w8][90 + l1] = ceq[l1];
            }
            if (l2 < 90) {
                const float r = sigf(giA[l2] + ghA[l2]);
                const float z = sigf(giA[90 + l2] + ghA[90 + l2]);
                const float g = tanhf_(giA[180 + l2] + r * ghA[180 + l2]);
                const float ns = (1.f - z) * g + z * ssv[l2];
                nsvW[w8][l2] = ns;
                xpW[w8][l2] = ns - ssv[l2];
                xpW[w8][90 + l2] = ceq[l2];
            }
        }
        {   // nsync (M=1)
            bf16x8 af[3];
#pragma unroll
            for (int kk = 0; kk < 3; ++kk)
                af[kk] = (lr == 0) ? cvt8(&nsvW[w8][kk * 32 + lh * 8]) : z8;
            const f32x4 d = mm3(af, symF + (size_t)w8 * 1536 + lane * 8);
            if (lh == 0) nsyL[m6] = (m6 < 90) ? d[0] : 0.f;
        }
        {   // pvec (M=1, K=192)
            f32x4 d = f32x4{0.f, 0.f, 0.f, 0.f};
            const unsigned short* bp = wprF + (size_t)w8 * 3072 + lane * 8;
#pragma unroll
            for (int kk = 0; kk < 6; ++kk) {
                const bf16x8 av = (lr == 0) ? cvt8(&xpW[w8][kk * 32 + lh * 8]) : z8;
                d = __builtin_amdgcn_mfma_f32_16x16x32_bf16(av, *(const bf16x8*)(bp + kk * 512), d, 0, 0, 0);
            }
            if (lh == 0) pvL[m6] = (m6 < 90) ? fmaxf(b_prop[m6] + d[0], 0.f) : 0.f;
        }
    } else if (owner) {
        // rfd MFMA on waves 6-7 (independent of nsync)
        const int nnb = nnbS;
        const int pairs = ((nnb + 15) >> 4) * 6;
        for (int p = w8 - 6; p < pairs; p += 2) {
            const int mt = p / 6, nt = p - mt * 6;
            bf16x8 af[3];
            const int jrow = mt * 16 + lr;
            if (jrow < nnb) {
                const float* rp = &hnb[jrow * 96];
#pragma unroll
                for (int kk = 0; kk < 3; ++kk) af[kk] = cvt8(rp + kk * 32 + lh * 8);
            } else { af[0] = z8; af[1] = z8; af[2] = z8; }
            const f32x4 d = mm3(af, syF + (size_t)nt * 1536 + lane * 8);
#pragma unroll
            for (int r4 = 0; r4 < 4; ++r4) {
                const int j = mt * 16 + lh * 4 + r4;
                const int m = nt * 16 + lr;
                if (j < nnb && m < 90)
                    rfd[j * 92 + m] = d[r4] + ws[OFF_CEB + (size_t)nblist[j] * 90 + m];
            }
        }
    }
    __syncthreads();   // ---- barrier 3 ----

    // ================= C: MFMA chains + gates (multi-pass; champion structure) ==========
    const int nact = nactS;
    const int npass0 = (nact + SLOTS - 1) / SLOTS;
    const int npass = (npass0 > 0) ? npass0 : 1;
    for (int pass = 0; pass < npass; ++pass) {
        const int e0p = pass * SLOTS;
        int e1p = e0p + SLOTS; if (e1p > nact) e1p = nact;
        const int na = e1p - e0p;

        // C1: act
        if (na > 0 && w8 < 6) {
            const int nt = w8;
            bf16x8 af[3];
            if (lr < na) {
                const float* rp = &hR[listS[e0p + lr] * 100];
#pragma unroll
                for (int kk = 0; kk < 3; ++kk) af[kk] = cvt8(rp + kk * 32 + lh * 8);
            } else { af[0] = z8; af[1] = z8; af[2] = z8; }
            const f32x4 d = mm3(af, syF + (size_t)nt * 1536 + lane * 8);
            const int m = nt * 16 + lr;
            if (m < 90) {
#pragma unroll
                for (int r4 = 0; r4 < 4; ++r4) {
                    const int slot = lh * 4 + r4;
                    if (slot >= na) continue;
                    const int r = listS[e0p + slot];
                    const float nv = nbvL[r], sv = svL[r];
                    float s = 0.f;
                    if (nv != 0.f)
                        s = nv * fmaxf(nsyL[m] + ws[OFF_CEB + (size_t)(k0 + r) * 90 + m] + d[r4], 0.f);
                    if (k0 + r == q) {
                        const int nnb = nnbS;
                        const float nm = nsyL[m];
                        for (int j = 0; j < nnb; ++j)
                            s += nbw[j] * fmaxf(nm + rfd[j * 92 + m], 0.f);
                    }
                    actb[slot * 96 + m] = 0.5f * s + 0.5f * sv * pvL[m];
                }
            }
        }
        __syncthreads();   // ---- barrier 4 ----

        // C2: inf
        if (na > 0 && w8 < 6) {
            const int nt = w8;
            bf16x8 af[3];
            if (lr < na) {
                const float* rp = &actb[lr * 96];
#pragma unroll
                for (int kk = 0; kk < 3; ++kk) af[kk] = cvt8(rp + kk * 32 + lh * 8);
            } else { af[0] = z8; af[1] = z8; af[2] = z8; }
            const f32x4 d = mm3(af, agF + (size_t)nt * 1536 + lane * 8);
            const int m = nt * 16 + lr;
            if (m < 90) {
#pragma unroll
                for (int r4 = 0; r4 < 4; ++r4) {
                    const int slot = lh * 4 + r4;
                    if (slot < na) infb[slot * 96 + m] = fmaxf(baggL[m] + d[r4], 0.f);
                }
            }
        }
        __syncthreads();   // ---- barrier 5 ----

        // C3: gi
        if (na > 0) {
            bf16x8 af[3];
            if (lr < na) {
                const float* rp = &infb[lr * 96];
#pragma unroll
                for (int kk = 0; kk < 3; ++kk) af[kk] = cvt8(rp + kk * 32 + lh * 8);
            } else { af[0] = z8; af[1] = z8; af[2] = z8; }
            for (int nt = w8; nt < 17; nt += 8) {
                const f32x4 d = mm3(af, wiF + (size_t)nt * 1536 + lane * 8);
                const int c = nt * 16 + lr;
                if (c < 270) {
#pragma unroll
                    for (int r4 = 0; r4 < 4; ++r4) {
                        const int slot = lh * 4 + r4;
                        if (slot < na) giL[slot * 273 + c] = biL[c] + d[r4];
                    }
                }
            }
        }
        __syncthreads();   // ---- barrier 6 ----

        // C4: gates (gh acc in registers); last pass ends the kernel (no barrier)
#pragma unroll
        for (int ct = 0; ct < 3; ++ct) {
            const int m = cg * 48 + ct * 16 + lr;
            if (m < 90) {
                const float bhr = bhL[m], bhz = bhL[90 + m], bhg = bhL[180 + m];
#pragma unroll
                for (int r4 = 0; r4 < 4; ++r4) {
                    const int row = rt * 16 + 4 * lh + r4;
                    const int sraw = rowslotS[row];
                    const bool mine = (sraw < 0) ? (pass == 0) : (sraw >= e0p && sraw < e1p);
                    if (!mine) continue;
                    const float* gs = (sraw < 0) ? gi0L : &giL[(sraw - e0p) * 273];
                    const float rg = sigf(gs[m] + acc[0][ct][r4] + bhr);
                    const float zg = sigf(gs[90 + m] + acc[1][ct][r4] + bhz);
                    const float gg = tanhf_(gs[180 + m] + rg * (acc[2][ct][r4] + bhg));
                    const float hold = hR[row * 100 + m];
                    const float hn = (1.f - zg) * gg + zg * hold;
                    hR[row * 100 + m] = hn;
                    stOut[((size_t)(bb * KU + k0 + row)) * 90 + m] = hn;
                }
            }
        }
        if (pass + 1 < npass) __syncthreads();
    }
}

// ============ finalize: out[NT-1] from final states ============
__global__ __launch_bounds__(512, 1) void skt_final(
    const float* __restrict__ stFinal, const float* __restrict__ W_out,
    const float* __restrict__ b_out, float* __restrict__ out) {
    const int tid = threadIdx.x;
    const int bb = blockIdx.x >> 3;
    const int k0 = (blockIdx.x & 7) * TIL;
    const int row = tid >> 3, j = tid & 7;
    const float* sp = stFinal + ((size_t)(bb * KU + k0 + row)) * 90;
    float p = 0.f;
#pragma unroll
    for (int mm = 0; mm < 12; ++mm) {
        const int m = j * 12 + mm;
        if (m < 90) p += sp[m] * W_out[m];
    }
#pragma unroll
    for (int o = 1; o < 8; o <<= 1) p += __shfl_xor(p, o);
    if (j == 0)
        out[(size_t)(NT - 1) * NB * KU + (size_t)bb * KU + k0 + row] = sigf(p + b_out[0]);
}

extern "C" void kernel_launch(void* const* d_in, const int* in_sizes, int n_in,
                              void* d_out, int out_size, void* d_ws, size_t ws_size,
                              hipStream_t stream) {
    const int* questions = (const int*)d_in[0];
    const int* answers = (const int*)d_in[1];
    const float* response_emb = (const float*)d_in[2];
    const float* concept_emb = (const float*)d_in[3];
    const float* nb_adj = (const float*)d_in[4];
    const float* succ_adj = (const float*)d_in[5];
    const float* Wi_self = (const float*)d_in[6];
    const float* Wh_self = (const float*)d_in[7];
    const float* bi_self = (const float*)d_in[8];
    const float* bh_self = (const float*)d_in[9];
    const float* Wi_rnn = (const float*)d_in[10];
    const float* Wh_rnn = (const float*)d_in[11];
    const float* bi_rnn = (const float*)d_in[12];
    const float* bh_rnn = (const float*)d_in[13];
    const float* W_sync = (const float*)d_in[14];
    const float* b_sync = (const float*)d_in[15];
    const float* W_prop = (const float*)d_in[16];
    const float* b_prop = (const float*)d_in[17];
    const float* W_agg = (const float*)d_in[18];
    const float* b_agg = (const float*)d_in[19];
    const float* W_out = (const float*)d_in[20];
    const float* b_out = (const float*)d_in[21];

    float* out = (float*)d_out;
    float* stFinal = out + (size_t)NT * NB * KU;   // states region of d_out
    float* ws = (float*)d_ws;

    // No memset needed: t=0 never reads states (in-kernel zero path) and every
    // state element is rewritten every step; final states land in stFinal at t=63.
    skt_prep<<<142, 256, 0, stream>>>(concept_emb, W_sync, b_sync, Wi_rnn, Wh_rnn,
                                      Wi_self, Wh_self, W_prop, bi_rnn, b_agg, W_agg, ws);
    for (int t = 0; t < NT; ++t) {
        const float* sin = (t & 1) ? ws : stFinal;
        float* sout = (t & 1) ? stFinal : ws;
        skt_step<<<NB * 8, 512, 0, stream>>>(
            questions, answers, response_emb, concept_emb, nb_adj, succ_adj,
            bi_self, bh_self, bi_rnn, bh_rnn, b_agg, b_prop, W_out, b_out,
            ws, sin, sout, out, t);
    }
    skt_final<<<NB * 8, 512, 0, stream>>>(stFinal, W_out, b_out, out);
}